// Round 1
// 567.047 us; speedup vs baseline: 1.0602x; 1.0602x over previous
//
#include <hip/hip_runtime.h>
#include <hip/hip_bf16.h>

// Problem constants (B=16, L=2048, D=1024, K=3)
#define D_    1024
#define LSEQ  2048
#define M_    32768            // B*L rows
#define K_    1024             // reduction dim
#define NT    16               // K_ / 64 K-tiles

typedef __bf16 bf16x8 __attribute__((ext_vector_type(8)));
typedef float  f32x4  __attribute__((ext_vector_type(4)));

__device__ __forceinline__ unsigned short f2bf(float f) {
  unsigned u = __float_as_uint(f);
  u += 0x7FFFu + ((u >> 16) & 1u);   // RNE
  return (unsigned short)(u >> 16);
}
__device__ __forceinline__ float bf2f(unsigned short h) {
  return __uint_as_float(((unsigned)h) << 16);
}

__device__ __forceinline__ void gload_lds16(const void* g, void* l) {
  __builtin_amdgcn_global_load_lds((const __attribute__((address_space(1))) void*)g,
                                   (__attribute__((address_space(3))) void*)l,
                                   16, 0, 0);
}

#define FENCE() asm volatile("" ::: "memory")
#define RBAR()  do { FENCE(); __builtin_amdgcn_s_barrier(); FENCE(); } while (0)

// ---------------- fused fp32 -> bf16 conversion (x, Win, Wout in one launch) ----------------
#define NX4  (M_ * K_ / 4)          // 8388608
#define NW4  (3072 * K_ / 4)        //  786432
#define NO4  (D_ * K_ / 4)          //  262144
__global__ __launch_bounds__(256) void cvt_all(const float* __restrict__ x,
                                               const float* __restrict__ Win,
                                               const float* __restrict__ Wout,
                                               unsigned short* __restrict__ x_b,
                                               unsigned short* __restrict__ Win_b,
                                               unsigned short* __restrict__ Wout_b) {
  int i = blockIdx.x * 256 + threadIdx.x;
  const float* src;
  unsigned short* dst;
  int off;
  if (i < NX4)            { src = x;    dst = x_b;    off = i; }
  else if (i < NX4 + NW4) { src = Win;  dst = Win_b;  off = i - NX4; }
  else                    { src = Wout; dst = Wout_b; off = i - NX4 - NW4; }
  float4 v = ((const float4*)src)[off];
  ushort4 o;
  o.x = f2bf(v.x); o.y = f2bf(v.y); o.z = f2bf(v.z); o.w = f2bf(v.w);
  ((ushort4*)dst)[off] = o;
}

// ---------------- shared 256x256 (K=1024) bf16 MFMA core ----------------
// 8 waves (2M x 4N), BK=64, double-buffered 128KiB LDS, 4 phases/K-tile,
// counted vmcnt(8) across tile boundaries (never drains mid-loop),
// XOR-swizzled LDS (chunk ^= row&7) via pre-swizzled global_load_lds source.

#define LDA(mh) do { _Pragma("unroll") \
  for (int f = 0; f < 4; ++f) { \
    const int o = aRow + ((mh) * 4 + f) * 2048; \
    av[f][0] = *(const bf16x8*)(As + o); \
    av[f][1] = *(const bf16x8*)(As + (o ^ 64)); \
  } } while (0)

#define LDB(nh, bb) do { _Pragma("unroll") \
  for (int f = 0; f < 2; ++f) { \
    const int o = bRow + ((nh) * 2 + f) * 2048; \
    bb[f][0] = *(const bf16x8*)(Bs + o); \
    bb[f][1] = *(const bf16x8*)(Bs + (o ^ 64)); \
  } } while (0)

#define MFMA_Q(mh, nh, bb) do { _Pragma("unroll") \
  for (int f = 0; f < 4; ++f) { _Pragma("unroll") \
    for (int gg = 0; gg < 2; ++gg) { \
      f32x4 cacc = acc[(mh) * 4 + f][(nh) * 2 + gg]; \
      cacc = __builtin_amdgcn_mfma_f32_16x16x32_bf16(av[f][0], bb[gg][0], cacc, 0, 0, 0); \
      cacc = __builtin_amdgcn_mfma_f32_16x16x32_bf16(av[f][1], bb[gg][1], cacc, 0, 0, 0); \
      acc[(mh) * 4 + f][(nh) * 2 + gg] = cacc; \
    } } } while (0)

__device__ __forceinline__ void gemm_core256(char* smem,
    const unsigned short* aBase,
    const unsigned short* b0p, const unsigned short* b1p,
    const unsigned short* b2p, const unsigned short* b3p,
    f32x4 acc[8][4]) {
  const int tid  = threadIdx.x;
  const int lane = tid & 63;
  const int wm   = (tid >> 6) >> 2;
  const int wn   = (tid >> 6) & 3;
  const int quad = lane >> 4;
  const int l16  = lane & 15;
  // swizzled frag-read byte offsets: chunk ^= (row & 7), row&7 == l16&7
  const int swz  = (quad ^ (l16 & 7)) << 4;
  const int aRow = ((wm << 7) + l16) * 128 + swz;
  const int bRow = ((wn << 6) + l16) * 128 + swz;

  auto STAGE = [&](int t) {
    char* lb = smem + ((t & 1) << 16);
    const int k0 = t << 6;
#pragma unroll
    for (int i = 0; i < 4; ++i)
      gload_lds16(aBase + ((long)i << 16) + k0, lb + tid * 16 + i * 8192);
    gload_lds16(b0p + k0, lb + 32768 + tid * 16);
    gload_lds16(b1p + k0, lb + 32768 + tid * 16 + 8192);
    gload_lds16(b2p + k0, lb + 32768 + tid * 16 + 16384);
    gload_lds16(b3p + k0, lb + 32768 + tid * 16 + 24576);
  };

  STAGE(0);
  STAGE(1);
  asm volatile("s_waitcnt vmcnt(8)" ::: "memory");
  RBAR();

  for (int t = 0; t < NT; ++t) {
    const char* As = smem + ((t & 1) << 16);
    const char* Bs = As + 32768;
    bf16x8 av[4][2], b0[2][2], b1[2][2];

    // phase 1: quadrant (0,0)
    LDA(0); LDB(0, b0);
    RBAR();
    __builtin_amdgcn_s_setprio(1); MFMA_Q(0, 0, b0); __builtin_amdgcn_s_setprio(0);
    RBAR();
    // phase 2: quadrant (0,1)
    LDB(1, b1);
    RBAR();
    __builtin_amdgcn_s_setprio(1); MFMA_Q(0, 1, b1); __builtin_amdgcn_s_setprio(0);
    RBAR();
    // phase 3: quadrant (1,1)
    LDA(1);
    RBAR();
    __builtin_amdgcn_s_setprio(1); MFMA_Q(1, 1, b1); __builtin_amdgcn_s_setprio(0);
    RBAR();
    // phase 4: quadrant (1,0)
    LDB(0, b0);
    RBAR();
    __builtin_amdgcn_s_setprio(1); MFMA_Q(1, 0, b0); __builtin_amdgcn_s_setprio(0);
    RBAR();

    // tile boundary: buf[t&1] fully consumed; refill it for tile t+2,
    // then wait for tile t+1 to have landed (t+2's 8 loads stay in flight).
    if (t + 2 < NT) {
      STAGE(t + 2);
      asm volatile("s_waitcnt vmcnt(8)" ::: "memory");
      RBAR();
    } else if (t + 2 == NT) {
      asm volatile("s_waitcnt vmcnt(0)" ::: "memory");
      RBAR();
    }
  }
}

// ---------------- unified in_proj GEMM (256x256 tiles) ----------------
// grid 1536, XCD-swizzled: xcd=g&7, u=g>>3, mrow=xcd+8*(u/12), c=u%12.
// c<8 : paired tile, B = [W_B rows c*128.. (128) ; W_x rows 2048+c*128.. (128)];
//       epilogue Bx = (Bg+b)*(xg+b)
// c>=8: plain tile,  B = W_C rows (c-8)*256..; epilogue Cg = acc+b
__global__ __launch_bounds__(512, 2) void gemm_inproj(const unsigned short* __restrict__ A,
                                                      const unsigned short* __restrict__ Wb,
                                                      const float* __restrict__ bin,
                                                      unsigned short* __restrict__ Bx,
                                                      unsigned short* __restrict__ Cg) {
  __shared__ __align__(16) char smem[131072];

  const int g  = blockIdx.x;
  const int u  = g >> 3;
  const int m0 = ((g & 7) + 8 * (u / 12)) * 256;
  const int c  = u % 12;
  const bool paired = (c < 8);

  const int tid  = threadIdx.x;
  const int lane = tid & 63;
  const int srow = ((tid >> 6) << 3) + (lane >> 3);      // staging row (0..63, +i*64)
  const int sch  = (lane & 7) ^ (lane >> 3);             // pre-swizzled source chunk

  const unsigned short* aBase = A + (long)(m0 + srow) * K_ + sch * 8;
  const unsigned short *b0p, *b1p, *b2p, *b3p;
  int n0;
  if (paired) {
    n0  = c * 128;
    b0p = Wb + (long)(n0 + srow) * K_ + sch * 8;           // W_B rows 0..127
    b1p = b0p + (long)64 * K_;
    b2p = Wb + (long)(2048 + n0 + srow) * K_ + sch * 8;    // W_x rows 128..255
    b3p = b2p + (long)64 * K_;
  } else {
    n0  = (c - 8) * 256;
    b0p = Wb + (long)(1024 + n0 + srow) * K_ + sch * 8;    // W_C rows
    b1p = b0p + (long)64 * K_;
    b2p = b0p + (long)128 * K_;
    b3p = b0p + (long)192 * K_;
  }

  f32x4 acc[8][4] = {};
  gemm_core256(smem, aBase, b0p, b1p, b2p, b3p, acc);

  // ---- epilogue: LDS transpose (32 rows x 256 cols fp32), fused bias + gate ----
  const int wm = (tid >> 6) >> 2, wn = (tid >> 6) & 3;
  const int quad = lane >> 4, l16 = lane & 15;
  float* tr = (float*)smem;

  float bvv[4];
#pragma unroll
  for (int ni = 0; ni < 4; ++ni) {
    int col = wn * 64 + ni * 16 + l16;
    bvv[ni] = paired ? ((col < 128) ? bin[n0 + col] : bin[2048 + n0 + col - 128])
                     : bin[1024 + n0 + col];
  }

  const int trr   = tid >> 4;
  const int tcc   = tid & 15;
  const int growb = m0 + ((trr >> 4) << 7) + (trr & 15);

#pragma unroll
  for (int mi = 0; mi < 8; ++mi) {
    __syncthreads();
#pragma unroll
    for (int ni = 0; ni < 4; ++ni) {
      int col = wn * 64 + ni * 16 + l16;
      f32x4 v = acc[mi][ni];
#pragma unroll
      for (int r = 0; r < 4; ++r)
        tr[(wm * 16 + quad * 4 + r) * 260 + col] = v[r] + bvv[ni];
    }
    __syncthreads();

    const int grow = growb + mi * 16;
    if (paired) {
#pragma unroll
      for (int j = 0; j < 2; ++j) {
        int cc = tcc * 4 + j * 64;
        f32x4 bg = *(const f32x4*)&tr[trr * 260 + cc];
        f32x4 xg = *(const f32x4*)&tr[trr * 260 + 128 + cc];
        ushort4 o;
        o.x = f2bf(bg[0] * xg[0]); o.y = f2bf(bg[1] * xg[1]);
        o.z = f2bf(bg[2] * xg[2]); o.w = f2bf(bg[3] * xg[3]);
        *(ushort4*)&Bx[(long)grow * D_ + n0 + cc] = o;
      }
    } else {
#pragma unroll
      for (int j = 0; j < 4; ++j) {
        int cc = tcc * 4 + j * 64;
        f32x4 v = *(const f32x4*)&tr[trr * 260 + cc];
        ushort4 o;
        o.x = f2bf(v[0]); o.y = f2bf(v[1]); o.z = f2bf(v[2]); o.w = f2bf(v[3]);
        *(ushort4*)&Cg[(long)grow * D_ + n0 + cc] = o;
      }
    }
  }
}

// ---------------- streaming causal conv + gate ----------------
__global__ __launch_bounds__(256) void conv_mul(const unsigned short* __restrict__ Bx,
                                                const unsigned short* __restrict__ Cg,
                                                const float* __restrict__ wconv,
                                                unsigned short* __restrict__ y) {
  __shared__ float wt[3][D_];
  for (int i = threadIdx.x; i < D_; i += 256) {
    wt[0][i] = wconv[i * 3 + 0];
    wt[1][i] = wconv[i * 3 + 1];
    wt[2][i] = wconv[i * 3 + 2];
  }
  __syncthreads();

  int idx = blockIdx.x * 256 + threadIdx.x;   // [0, 32768*128)
  int bl  = idx >> 7;
  int d8  = (idx & 127) * 8;
  int l   = bl & (LSEQ - 1);

  typedef unsigned short us8 __attribute__((ext_vector_type(8)));
  us8 zz = {0, 0, 0, 0, 0, 0, 0, 0};
  us8 x0 = *(const us8*)&Bx[(long)bl * D_ + d8];
  us8 x1 = (l >= 1) ? *(const us8*)&Bx[(long)(bl - 1) * D_ + d8] : zz;
  us8 x2 = (l >= 2) ? *(const us8*)&Bx[(long)(bl - 2) * D_ + d8] : zz;
  us8 cg = *(const us8*)&Cg[(long)bl * D_ + d8];

  us8 o;
#pragma unroll
  for (int j = 0; j < 8; ++j) {
    float conv = wt[0][d8 + j] * bf2f(x2[j]) + wt[1][d8 + j] * bf2f(x1[j])
               + wt[2][d8 + j] * bf2f(x0[j]);
    o[j] = f2bf(bf2f(cg[j]) * conv);
  }
  *(us8*)&y[(long)bl * D_ + d8] = o;
}

// ---------------- out_proj GEMM (256x256 tiles, fp32 out) ----------------
// grid 512, XCD-swizzled: mrow=(g&7)+8*((g>>3)>>2), c=(g>>3)&3
__global__ __launch_bounds__(512, 2) void gemm_out(const unsigned short* __restrict__ A,
                                                   const unsigned short* __restrict__ Wb,
                                                   const float* __restrict__ bias,
                                                   float* __restrict__ Out) {
  __shared__ __align__(16) char smem[131072];

  const int g  = blockIdx.x;
  const int u  = g >> 3;
  const int m0 = ((g & 7) + 8 * (u >> 2)) * 256;
  const int n0 = (u & 3) * 256;

  const int tid  = threadIdx.x;
  const int lane = tid & 63;
  const int srow = ((tid >> 6) << 3) + (lane >> 3);
  const int sch  = (lane & 7) ^ (lane >> 3);

  const unsigned short* aBase = A + (long)(m0 + srow) * K_ + sch * 8;
  const unsigned short* b0p   = Wb + (long)(n0 + srow) * K_ + sch * 8;

  f32x4 acc[8][4] = {};
  gemm_core256(smem, aBase, b0p, b0p + (long)64 * K_, b0p + (long)128 * K_,
               b0p + (long)192 * K_, acc);

  const int wm = (tid >> 6) >> 2, wn = (tid >> 6) & 3;
  const int quad = lane >> 4, l16 = lane & 15;
  float* tr = (float*)smem;

  float bvv[4];
#pragma unroll
  for (int ni = 0; ni < 4; ++ni)
    bvv[ni] = bias[n0 + wn * 64 + ni * 16 + l16];

  const int trr   = tid >> 4;
  const int tcc   = tid & 15;
  const int growb = m0 + ((trr >> 4) << 7) + (trr & 15);

#pragma unroll
  for (int mi = 0; mi < 8; ++mi) {
    __syncthreads();
#pragma unroll
    for (int ni = 0; ni < 4; ++ni) {
      int col = wn * 64 + ni * 16 + l16;
      f32x4 v = acc[mi][ni];
#pragma unroll
      for (int r = 0; r < 4; ++r)
        tr[(wm * 16 + quad * 4 + r) * 260 + col] = v[r] + bvv[ni];
    }
    __syncthreads();

    const int grow = growb + mi * 16;
#pragma unroll
    for (int j = 0; j < 4; ++j) {
      int cc = tcc * 4 + j * 64;
      *(f32x4*)&Out[(long)grow * D_ + n0 + cc] = *(const f32x4*)&tr[trr * 260 + cc];
    }
  }
}

// ---------------- launch ----------------
extern "C" void kernel_launch(void* const* d_in, const int* in_sizes, int n_in,
                              void* d_out, int out_size, void* d_ws, size_t ws_size,
                              hipStream_t stream) {
  const float* x     = (const float*)d_in[0];
  const float* Win   = (const float*)d_in[1];
  const float* bin   = (const float*)d_in[2];
  const float* wconv = (const float*)d_in[3];
  const float* Wout  = (const float*)d_in[4];
  const float* bout  = (const float*)d_in[5];

  char* ws = (char*)d_ws;
  // ws: x_b 67,108,864 | Win_b 6,291,456 | Wout_b 2,097,152 | Bx 67,108,864 | Cg 67,108,864 | y 67,108,864
  unsigned short* x_b    = (unsigned short*)(ws);
  unsigned short* Win_b  = (unsigned short*)(ws + 67108864);
  unsigned short* Wout_b = (unsigned short*)(ws + 73400320);
  unsigned short* Bx_b   = (unsigned short*)(ws + 75497472);
  unsigned short* Cg_b   = (unsigned short*)(ws + 142606336);
  unsigned short* y_b    = (unsigned short*)(ws + 209715200);

  cvt_all<<<(NX4 + NW4 + NO4) / 256, 256, 0, stream>>>(x, Win, Wout, x_b, Win_b, Wout_b);

  gemm_inproj<<<1536, 512, 0, stream>>>(x_b, Win_b, bin, Bx_b, Cg_b);

  conv_mul<<<(M_ * (D_ / 8)) / 256, 256, 0, stream>>>(Bx_b, Cg_b, wconv, y_b);

  gemm_out<<<512, 512, 0, stream>>>(y_b, Wout_b, bout, (float*)d_out);
}

// Round 2
// 546.595 us; speedup vs baseline: 1.0999x; 1.0374x over previous
//
#include <hip/hip_runtime.h>
#include <hip/hip_bf16.h>

// Problem constants (B=16, L=2048, D=1024, K=3)
#define D_    1024
#define LSEQ  2048
#define M_    32768            // B*L rows
#define K_    1024             // reduction dim
#define NT    16               // K_ / 64 K-tiles

typedef __bf16 bf16x8 __attribute__((ext_vector_type(8)));
typedef float  f32x4  __attribute__((ext_vector_type(4)));

__device__ __forceinline__ unsigned short f2bf(float f) {
  unsigned u = __float_as_uint(f);
  u += 0x7FFFu + ((u >> 16) & 1u);   // RNE
  return (unsigned short)(u >> 16);
}
__device__ __forceinline__ float bf2f(unsigned short h) {
  return __uint_as_float(((unsigned)h) << 16);
}

__device__ __forceinline__ void gload_lds16(const void* g, void* l) {
  __builtin_amdgcn_global_load_lds((const __attribute__((address_space(1))) void*)g,
                                   (__attribute__((address_space(3))) void*)l,
                                   16, 0, 0);
}

#define FENCE() asm volatile("" ::: "memory")
#define RBAR()  do { FENCE(); __builtin_amdgcn_s_barrier(); FENCE(); } while (0)

// ---------------- fused fp32 -> bf16 conversion (x, Win, Wout in one launch) ----------------
#define NX4  (M_ * K_ / 4)          // 8388608
#define NW4  (3072 * K_ / 4)        //  786432
#define NO4  (D_ * K_ / 4)          //  262144
__global__ __launch_bounds__(256) void cvt_all(const float* __restrict__ x,
                                               const float* __restrict__ Win,
                                               const float* __restrict__ Wout,
                                               unsigned short* __restrict__ x_b,
                                               unsigned short* __restrict__ Win_b,
                                               unsigned short* __restrict__ Wout_b) {
  int i = blockIdx.x * 256 + threadIdx.x;
  const float* src;
  unsigned short* dst;
  int off;
  if (i < NX4)            { src = x;    dst = x_b;    off = i; }
  else if (i < NX4 + NW4) { src = Win;  dst = Win_b;  off = i - NX4; }
  else                    { src = Wout; dst = Wout_b; off = i - NX4 - NW4; }
  float4 v = ((const float4*)src)[off];
  ushort4 o;
  o.x = f2bf(v.x); o.y = f2bf(v.y); o.z = f2bf(v.z); o.w = f2bf(v.w);
  ((ushort4*)dst)[off] = o;
}

// ---------------- shared 256x256 (K=1024) bf16 MFMA core ----------------
// 8 waves (2M x 4N), BK=64, double-buffered 128KiB LDS.
// Quadrant order (0,0)->(0,1)->(1,1)->(1,0); b0 stays live across the tile.
// Fragment ds_reads pipelined one phase ahead (counted lgkm, never drained
// mid-tile); av registers reused for mh=1 via per-fragment interleaved reload.
// STAGE(t+2) issued under phase-3 MFMA; vmcnt(8) across tile boundaries.
// LDS XOR-swizzle (chunk ^= row&7) via pre-swizzled global source.

__device__ __forceinline__ void gemm_core256(char* smem,
    const unsigned short* aBase,
    const unsigned short* b0p, const unsigned short* b1p,
    const unsigned short* b2p, const unsigned short* b3p,
    f32x4 acc[8][4]) {
  const int tid  = threadIdx.x;
  const int lane = tid & 63;
  const int wm   = (tid >> 6) >> 2;
  const int wn   = (tid >> 6) & 3;
  const int quad = lane >> 4;
  const int l16  = lane & 15;
  // swizzled frag-read byte offsets: chunk ^= (row & 7), row&7 == l16&7
  const int swz  = (quad ^ (l16 & 7)) << 4;
  const int aRow = ((wm << 7) + l16) * 128 + swz;
  const int bRow = ((wn << 6) + l16) * 128 + swz;

  auto STAGE = [&](int t) {
    char* lb = smem + ((t & 1) << 16);
    const int k0 = t << 6;
#pragma unroll
    for (int i = 0; i < 4; ++i)
      gload_lds16(aBase + ((long)i << 16) + k0, lb + tid * 16 + i * 8192);
    gload_lds16(b0p + k0, lb + 32768 + tid * 16);
    gload_lds16(b1p + k0, lb + 32768 + tid * 16 + 8192);
    gload_lds16(b2p + k0, lb + 32768 + tid * 16 + 16384);
    gload_lds16(b3p + k0, lb + 32768 + tid * 16 + 24576);
  };

  STAGE(0);
  STAGE(1);
  asm volatile("s_waitcnt vmcnt(8)" ::: "memory");
  RBAR();

  bf16x8 av[4][2], b0[2][2], b1[2][2];

  for (int t = 0; t < NT; ++t) {
    const char* As = smem + ((t & 1) << 16);
    const char* Bs = As + 32768;

    // ---- phase-0 fragment loads: b0, av(mh=0), then b1 prefetch (last) ----
#pragma unroll
    for (int f = 0; f < 2; ++f) {
      const int o = bRow + f * 2048;
      b0[f][0] = *(const bf16x8*)(Bs + o);
      b0[f][1] = *(const bf16x8*)(Bs + (o ^ 64));
    }
#pragma unroll
    for (int f = 0; f < 4; ++f) {
      const int o = aRow + f * 2048;
      av[f][0] = *(const bf16x8*)(As + o);
      av[f][1] = *(const bf16x8*)(As + (o ^ 64));
    }
#pragma unroll
    for (int f = 0; f < 2; ++f) {
      const int o = bRow + (2 + f) * 2048;
      b1[f][0] = *(const bf16x8*)(Bs + o);
      b1[f][1] = *(const bf16x8*)(Bs + (o ^ 64));
    }
    RBAR();

    // ---- phase 0: quadrant (0,0) — waits lgkm(4), b1 drains underneath ----
    __builtin_amdgcn_s_setprio(1);
#pragma unroll
    for (int f = 0; f < 4; ++f)
#pragma unroll
      for (int gg = 0; gg < 2; ++gg) {
        f32x4 c = acc[f][gg];
        c = __builtin_amdgcn_mfma_f32_16x16x32_bf16(av[f][0], b0[gg][0], c, 0, 0, 0);
        c = __builtin_amdgcn_mfma_f32_16x16x32_bf16(av[f][1], b0[gg][1], c, 0, 0, 0);
        acc[f][gg] = c;
      }
    __builtin_amdgcn_s_setprio(0);
    RBAR();

    // ---- phase 1: quadrant (0,1), per-f reload av <- mh=1 rows ----
    __builtin_amdgcn_s_setprio(1);
#pragma unroll
    for (int f = 0; f < 4; ++f) {
#pragma unroll
      for (int gg = 0; gg < 2; ++gg) {
        f32x4 c = acc[f][2 + gg];
        c = __builtin_amdgcn_mfma_f32_16x16x32_bf16(av[f][0], b1[gg][0], c, 0, 0, 0);
        c = __builtin_amdgcn_mfma_f32_16x16x32_bf16(av[f][1], b1[gg][1], c, 0, 0, 0);
        acc[f][2 + gg] = c;
      }
      const int o = aRow + (4 + f) * 2048;
      av[f][0] = *(const bf16x8*)(As + o);
      av[f][1] = *(const bf16x8*)(As + (o ^ 64));
    }
    __builtin_amdgcn_s_setprio(0);
    RBAR();

    // ---- phase 2: quadrant (1,1) — av reloads drain underneath ----
    __builtin_amdgcn_s_setprio(1);
#pragma unroll
    for (int f = 0; f < 4; ++f)
#pragma unroll
      for (int gg = 0; gg < 2; ++gg) {
        f32x4 c = acc[4 + f][2 + gg];
        c = __builtin_amdgcn_mfma_f32_16x16x32_bf16(av[f][0], b1[gg][0], c, 0, 0, 0);
        c = __builtin_amdgcn_mfma_f32_16x16x32_bf16(av[f][1], b1[gg][1], c, 0, 0, 0);
        acc[4 + f][2 + gg] = c;
      }
    __builtin_amdgcn_s_setprio(0);
    RBAR();
    // all waves' ds_reads of buf[t] have retired past this barrier
    // (each wave hit lgkm(0) on its av reloads before its phase-2 MFMAs)

    // ---- phase 3: quadrant (1,0); STAGE(t+2) issues under the MFMAs ----
    if (t + 2 < NT) STAGE(t + 2);
    __builtin_amdgcn_s_setprio(1);
#pragma unroll
    for (int f = 0; f < 4; ++f)
#pragma unroll
      for (int gg = 0; gg < 2; ++gg) {
        f32x4 c = acc[4 + f][gg];
        c = __builtin_amdgcn_mfma_f32_16x16x32_bf16(av[f][0], b0[gg][0], c, 0, 0, 0);
        c = __builtin_amdgcn_mfma_f32_16x16x32_bf16(av[f][1], b0[gg][1], c, 0, 0, 0);
        acc[4 + f][gg] = c;
      }
    __builtin_amdgcn_s_setprio(0);

    // tile boundary: ensure buf[t+1] staging landed; t+2's loads stay in flight
    if (t + 2 < NT) {
      asm volatile("s_waitcnt vmcnt(8)" ::: "memory");
      RBAR();
    } else if (t + 2 == NT) {
      asm volatile("s_waitcnt vmcnt(0)" ::: "memory");
      RBAR();
    }
  }
}

// ---------------- unified in_proj GEMM (256x256 tiles) ----------------
// grid 1536, XCD-swizzled: xcd=g&7, u=g>>3, mrow=xcd+8*(u/12), c=u%12.
// c<8 : paired tile, B = [W_B rows c*128.. (128) ; W_x rows 2048+c*128.. (128)];
//       epilogue Bx = (Bg+b)*(xg+b)
// c>=8: plain tile,  B = W_C rows (c-8)*256..; epilogue Cg = acc+b
__global__ __launch_bounds__(512, 2) void gemm_inproj(const unsigned short* __restrict__ A,
                                                      const unsigned short* __restrict__ Wb,
                                                      const float* __restrict__ bin,
                                                      unsigned short* __restrict__ Bx,
                                                      unsigned short* __restrict__ Cg) {
  __shared__ __align__(16) char smem[131072];

  const int g  = blockIdx.x;
  const int u  = g >> 3;
  const int m0 = ((g & 7) + 8 * (u / 12)) * 256;
  const int c  = u % 12;
  const bool paired = (c < 8);

  const int tid  = threadIdx.x;
  const int lane = tid & 63;
  const int srow = ((tid >> 6) << 3) + (lane >> 3);      // staging row (0..63, +i*64)
  const int sch  = (lane & 7) ^ (lane >> 3);             // pre-swizzled source chunk

  const unsigned short* aBase = A + (long)(m0 + srow) * K_ + sch * 8;
  const unsigned short *b0p, *b1p, *b2p, *b3p;
  int n0;
  if (paired) {
    n0  = c * 128;
    b0p = Wb + (long)(n0 + srow) * K_ + sch * 8;           // W_B rows 0..127
    b1p = b0p + (long)64 * K_;
    b2p = Wb + (long)(2048 + n0 + srow) * K_ + sch * 8;    // W_x rows 128..255
    b3p = b2p + (long)64 * K_;
  } else {
    n0  = (c - 8) * 256;
    b0p = Wb + (long)(1024 + n0 + srow) * K_ + sch * 8;    // W_C rows
    b1p = b0p + (long)64 * K_;
    b2p = b0p + (long)128 * K_;
    b3p = b0p + (long)192 * K_;
  }

  f32x4 acc[8][4] = {};
  gemm_core256(smem, aBase, b0p, b1p, b2p, b3p, acc);

  // ---- epilogue: LDS transpose (32 rows x 256 cols fp32), fused bias + gate ----
  const int wm = (tid >> 6) >> 2, wn = (tid >> 6) & 3;
  const int quad = lane >> 4, l16 = lane & 15;
  float* tr = (float*)smem;

  float bvv[4];
#pragma unroll
  for (int ni = 0; ni < 4; ++ni) {
    int col = wn * 64 + ni * 16 + l16;
    bvv[ni] = paired ? ((col < 128) ? bin[n0 + col] : bin[2048 + n0 + col - 128])
                     : bin[1024 + n0 + col];
  }

  const int trr   = tid >> 4;
  const int tcc   = tid & 15;
  const int growb = m0 + ((trr >> 4) << 7) + (trr & 15);

#pragma unroll
  for (int mi = 0; mi < 8; ++mi) {
    __syncthreads();
#pragma unroll
    for (int ni = 0; ni < 4; ++ni) {
      int col = wn * 64 + ni * 16 + l16;
      f32x4 v = acc[mi][ni];
#pragma unroll
      for (int r = 0; r < 4; ++r)
        tr[(wm * 16 + quad * 4 + r) * 260 + col] = v[r] + bvv[ni];
    }
    __syncthreads();

    const int grow = growb + mi * 16;
    if (paired) {
#pragma unroll
      for (int j = 0; j < 2; ++j) {
        int cc = tcc * 4 + j * 64;
        f32x4 bg = *(const f32x4*)&tr[trr * 260 + cc];
        f32x4 xg = *(const f32x4*)&tr[trr * 260 + 128 + cc];
        ushort4 o;
        o.x = f2bf(bg[0] * xg[0]); o.y = f2bf(bg[1] * xg[1]);
        o.z = f2bf(bg[2] * xg[2]); o.w = f2bf(bg[3] * xg[3]);
        *(ushort4*)&Bx[(long)grow * D_ + n0 + cc] = o;
      }
    } else {
#pragma unroll
      for (int j = 0; j < 4; ++j) {
        int cc = tcc * 4 + j * 64;
        f32x4 v = *(const f32x4*)&tr[trr * 260 + cc];
        ushort4 o;
        o.x = f2bf(v[0]); o.y = f2bf(v[1]); o.z = f2bf(v[2]); o.w = f2bf(v[3]);
        *(ushort4*)&Cg[(long)grow * D_ + n0 + cc] = o;
      }
    }
  }
}

// ---------------- streaming causal conv + gate ----------------
__global__ __launch_bounds__(256) void conv_mul(const unsigned short* __restrict__ Bx,
                                                const unsigned short* __restrict__ Cg,
                                                const float* __restrict__ wconv,
                                                unsigned short* __restrict__ y) {
  __shared__ float wt[3][D_];
  for (int i = threadIdx.x; i < D_; i += 256) {
    wt[0][i] = wconv[i * 3 + 0];
    wt[1][i] = wconv[i * 3 + 1];
    wt[2][i] = wconv[i * 3 + 2];
  }
  __syncthreads();

  int idx = blockIdx.x * 256 + threadIdx.x;   // [0, 32768*128)
  int bl  = idx >> 7;
  int d8  = (idx & 127) * 8;
  int l   = bl & (LSEQ - 1);

  typedef unsigned short us8 __attribute__((ext_vector_type(8)));
  us8 zz = {0, 0, 0, 0, 0, 0, 0, 0};
  us8 x0 = *(const us8*)&Bx[(long)bl * D_ + d8];
  us8 x1 = (l >= 1) ? *(const us8*)&Bx[(long)(bl - 1) * D_ + d8] : zz;
  us8 x2 = (l >= 2) ? *(const us8*)&Bx[(long)(bl - 2) * D_ + d8] : zz;
  us8 cg = *(const us8*)&Cg[(long)bl * D_ + d8];

  us8 o;
#pragma unroll
  for (int j = 0; j < 8; ++j) {
    float conv = wt[0][d8 + j] * bf2f(x2[j]) + wt[1][d8 + j] * bf2f(x1[j])
               + wt[2][d8 + j] * bf2f(x0[j]);
    o[j] = f2bf(bf2f(cg[j]) * conv);
  }
  *(us8*)&y[(long)bl * D_ + d8] = o;
}

// ---------------- out_proj GEMM (256x256 tiles, fp32 out) ----------------
// grid 512, XCD-swizzled: mrow=(g&7)+8*((g>>3)>>2), c=(g>>3)&3
__global__ __launch_bounds__(512, 2) void gemm_out(const unsigned short* __restrict__ A,
                                                   const unsigned short* __restrict__ Wb,
                                                   const float* __restrict__ bias,
                                                   float* __restrict__ Out) {
  __shared__ __align__(16) char smem[131072];

  const int g  = blockIdx.x;
  const int u  = g >> 3;
  const int m0 = ((g & 7) + 8 * (u >> 2)) * 256;
  const int n0 = (u & 3) * 256;

  const int tid  = threadIdx.x;
  const int lane = tid & 63;
  const int srow = ((tid >> 6) << 3) + (lane >> 3);
  const int sch  = (lane & 7) ^ (lane >> 3);

  const unsigned short* aBase = A + (long)(m0 + srow) * K_ + sch * 8;
  const unsigned short* b0p   = Wb + (long)(n0 + srow) * K_ + sch * 8;

  f32x4 acc[8][4] = {};
  gemm_core256(smem, aBase, b0p, b0p + (long)64 * K_, b0p + (long)128 * K_,
               b0p + (long)192 * K_, acc);

  const int wm = (tid >> 6) >> 2, wn = (tid >> 6) & 3;
  const int quad = lane >> 4, l16 = lane & 15;
  float* tr = (float*)smem;

  float bvv[4];
#pragma unroll
  for (int ni = 0; ni < 4; ++ni)
    bvv[ni] = bias[n0 + wn * 64 + ni * 16 + l16];

  const int trr   = tid >> 4;
  const int tcc   = tid & 15;
  const int growb = m0 + ((trr >> 4) << 7) + (trr & 15);

#pragma unroll
  for (int mi = 0; mi < 8; ++mi) {
    __syncthreads();
#pragma unroll
    for (int ni = 0; ni < 4; ++ni) {
      int col = wn * 64 + ni * 16 + l16;
      f32x4 v = acc[mi][ni];
#pragma unroll
      for (int r = 0; r < 4; ++r)
        tr[(wm * 16 + quad * 4 + r) * 260 + col] = v[r] + bvv[ni];
    }
    __syncthreads();

    const int grow = growb + mi * 16;
#pragma unroll
    for (int j = 0; j < 4; ++j) {
      int cc = tcc * 4 + j * 64;
      *(f32x4*)&Out[(long)grow * D_ + n0 + cc] = *(const f32x4*)&tr[trr * 260 + cc];
    }
  }
}

// ---------------- launch ----------------
extern "C" void kernel_launch(void* const* d_in, const int* in_sizes, int n_in,
                              void* d_out, int out_size, void* d_ws, size_t ws_size,
                              hipStream_t stream) {
  const float* x     = (const float*)d_in[0];
  const float* Win   = (const float*)d_in[1];
  const float* bin   = (const float*)d_in[2];
  const float* wconv = (const float*)d_in[3];
  const float* Wout  = (const float*)d_in[4];
  const float* bout  = (const float*)d_in[5];

  char* ws = (char*)d_ws;
  // ws: x_b 67,108,864 | Win_b 6,291,456 | Wout_b 2,097,152 | Bx 67,108,864 | Cg 67,108,864 | y 67,108,864
  unsigned short* x_b    = (unsigned short*)(ws);
  unsigned short* Win_b  = (unsigned short*)(ws + 67108864);
  unsigned short* Wout_b = (unsigned short*)(ws + 73400320);
  unsigned short* Bx_b   = (unsigned short*)(ws + 75497472);
  unsigned short* Cg_b   = (unsigned short*)(ws + 142606336);
  unsigned short* y_b    = (unsigned short*)(ws + 209715200);

  cvt_all<<<(NX4 + NW4 + NO4) / 256, 256, 0, stream>>>(x, Win, Wout, x_b, Win_b, Wout_b);

  gemm_inproj<<<1536, 512, 0, stream>>>(x_b, Win_b, bin, Bx_b, Cg_b);

  conv_mul<<<(M_ * (D_ / 8)) / 256, 256, 0, stream>>>(Bx_b, Cg_b, wconv, y_b);

  gemm_out<<<512, 512, 0, stream>>>(y_b, Wout_b, bout, (float*)d_out);
}

// Round 5
// 537.604 us; speedup vs baseline: 1.1183x; 1.0167x over previous
//
#include <hip/hip_runtime.h>
#include <hip/hip_bf16.h>

// Problem constants (B=16, L=2048, D=1024, K=3)
#define D_    1024
#define LSEQ  2048
#define M_    32768            // B*L rows
#define K_    1024             // reduction dim
#define NT    16               // K_ / 64 K-tiles

typedef __bf16 bf16x8 __attribute__((ext_vector_type(8)));
typedef float  f32x4  __attribute__((ext_vector_type(4)));

__device__ __forceinline__ unsigned short f2bf(float f) {
  unsigned u = __float_as_uint(f);
  u += 0x7FFFu + ((u >> 16) & 1u);   // RNE
  return (unsigned short)(u >> 16);
}
__device__ __forceinline__ float bf2f(unsigned short h) {
  return __uint_as_float(((unsigned)h) << 16);
}

__device__ __forceinline__ void gload_lds16(const void* g, void* l) {
  __builtin_amdgcn_global_load_lds((const __attribute__((address_space(1))) void*)g,
                                   (__attribute__((address_space(3))) void*)l,
                                   16, 0, 0);
}

#define FENCE() asm volatile("" ::: "memory")
#define RBAR()  do { FENCE(); __builtin_amdgcn_s_barrier(); FENCE(); } while (0)

// ---------------- fused fp32 -> bf16 conversion (x, Win, Wout in one launch) ----------------
#define NX4  (M_ * K_ / 4)          // 8388608
#define NW4  (3072 * K_ / 4)        //  786432
#define NO4  (D_ * K_ / 4)          //  262144
__global__ __launch_bounds__(256) void cvt_all(const float* __restrict__ x,
                                               const float* __restrict__ Win,
                                               const float* __restrict__ Wout,
                                               unsigned short* __restrict__ x_b,
                                               unsigned short* __restrict__ Win_b,
                                               unsigned short* __restrict__ Wout_b) {
  int i = blockIdx.x * 256 + threadIdx.x;
  const float* src;
  unsigned short* dst;
  int off;
  if (i < NX4)            { src = x;    dst = x_b;    off = i; }
  else if (i < NX4 + NW4) { src = Win;  dst = Win_b;  off = i - NX4; }
  else                    { src = Wout; dst = Wout_b; off = i - NX4 - NW4; }
  float4 v = ((const float4*)src)[off];
  ushort4 o;
  o.x = f2bf(v.x); o.y = f2bf(v.y); o.z = f2bf(v.z); o.w = f2bf(v.w);
  ((ushort4*)dst)[off] = o;
}

// ---------------- shared 256x256 (K=1024) bf16 MFMA core ----------------
// 8 waves (2M x 4N), BK=64, double-buffered 128KiB LDS.
// 2 barriers per K-tile (WAR before STAGE, publish after counted vmcnt).
// Loads interleaved with MFMA quadrants in source order (low register
// liveness); scheduler may hoist independent ds_reads under MFMAs via
// counted lgkmcnt.  Hard WAR pin: s_waitcnt lgkmcnt(0) + sched_barrier(0)
// immediately before the WAR barrier (rule #18: MFMAs/waits can otherwise
// move across inline-asm barriers).  Counted vmcnt(8) cross-tile.
// LDS XOR-swizzle (chunk ^= row&7) via pre-swizzled global source.

__device__ __forceinline__ void gemm_core256(char* smem,
    const unsigned short* aBase,
    const unsigned short* b0p, const unsigned short* b1p,
    const unsigned short* b2p, const unsigned short* b3p,
    f32x4 acc[8][4]) {
  const int tid  = threadIdx.x;
  const int lane = tid & 63;
  const int wm   = (tid >> 6) >> 2;
  const int wn   = (tid >> 6) & 3;
  const int quad = lane >> 4;
  const int l16  = lane & 15;
  // swizzled frag-read byte offsets: chunk ^= (row & 7), row&7 == l16&7
  const int swz  = (quad ^ (l16 & 7)) << 4;
  const int aRow = ((wm << 7) + l16) * 128 + swz;
  const int bRow = ((wn << 6) + l16) * 128 + swz;

  auto STAGE = [&](int t) {
    char* lb = smem + ((t & 1) << 16);
    const int k0 = t << 6;
#pragma unroll
    for (int i = 0; i < 4; ++i)
      gload_lds16(aBase + ((long)i << 16) + k0, lb + tid * 16 + i * 8192);
    gload_lds16(b0p + k0, lb + 32768 + tid * 16);
    gload_lds16(b1p + k0, lb + 32768 + tid * 16 + 8192);
    gload_lds16(b2p + k0, lb + 32768 + tid * 16 + 16384);
    gload_lds16(b3p + k0, lb + 32768 + tid * 16 + 24576);
  };

  STAGE(0);
  STAGE(1);
  asm volatile("s_waitcnt vmcnt(8)" ::: "memory");
  RBAR();

  for (int t = 0; t < NT; ++t) {
    const char* As = smem + ((t & 1) << 16);
    const char* Bs = As + 32768;

    bf16x8 b0[2][2], b1[2][2], av0[4][2], av1[4][2];

    // ---- loads for Q(0,0): b0, av0 ----
#pragma unroll
    for (int f = 0; f < 2; ++f) {
      const int o = bRow + f * 2048;
      b0[f][0] = *(const bf16x8*)(Bs + o);
      b0[f][1] = *(const bf16x8*)(Bs + (o ^ 64));
    }
#pragma unroll
    for (int f = 0; f < 4; ++f) {
      const int o = aRow + f * 2048;
      av0[f][0] = *(const bf16x8*)(As + o);
      av0[f][1] = *(const bf16x8*)(As + (o ^ 64));
    }

    // ---- Q(0,0) ----
    __builtin_amdgcn_s_setprio(1);
#pragma unroll
    for (int f = 0; f < 4; ++f)
#pragma unroll
      for (int gg = 0; gg < 2; ++gg) {
        f32x4 c = acc[f][gg];
        c = __builtin_amdgcn_mfma_f32_16x16x32_bf16(av0[f][0], b0[gg][0], c, 0, 0, 0);
        c = __builtin_amdgcn_mfma_f32_16x16x32_bf16(av0[f][1], b0[gg][1], c, 0, 0, 0);
        acc[f][gg] = c;
      }
    __builtin_amdgcn_s_setprio(0);

    // ---- loads b1; Q(0,1) ----
#pragma unroll
    for (int f = 0; f < 2; ++f) {
      const int o = bRow + (2 + f) * 2048;
      b1[f][0] = *(const bf16x8*)(Bs + o);
      b1[f][1] = *(const bf16x8*)(Bs + (o ^ 64));
    }
    __builtin_amdgcn_s_setprio(1);
#pragma unroll
    for (int f = 0; f < 4; ++f)
#pragma unroll
      for (int gg = 0; gg < 2; ++gg) {
        f32x4 c = acc[f][2 + gg];
        c = __builtin_amdgcn_mfma_f32_16x16x32_bf16(av0[f][0], b1[gg][0], c, 0, 0, 0);
        c = __builtin_amdgcn_mfma_f32_16x16x32_bf16(av0[f][1], b1[gg][1], c, 0, 0, 0);
        acc[f][2 + gg] = c;
      }
    __builtin_amdgcn_s_setprio(0);

    // ---- loads av1; Q(1,1) ----
#pragma unroll
    for (int f = 0; f < 4; ++f) {
      const int o = aRow + (4 + f) * 2048;
      av1[f][0] = *(const bf16x8*)(As + o);
      av1[f][1] = *(const bf16x8*)(As + (o ^ 64));
    }
    __builtin_amdgcn_s_setprio(1);
#pragma unroll
    for (int f = 0; f < 4; ++f)
#pragma unroll
      for (int gg = 0; gg < 2; ++gg) {
        f32x4 c = acc[4 + f][2 + gg];
        c = __builtin_amdgcn_mfma_f32_16x16x32_bf16(av1[f][0], b1[gg][0], c, 0, 0, 0);
        c = __builtin_amdgcn_mfma_f32_16x16x32_bf16(av1[f][1], b1[gg][1], c, 0, 0, 0);
        acc[4 + f][2 + gg] = c;
      }
    __builtin_amdgcn_s_setprio(0);

    // ---- hard WAR pin: all of this wave's buf[t] ds_reads retired ----
    asm volatile("s_waitcnt lgkmcnt(0)" ::: "memory");
    __builtin_amdgcn_sched_barrier(0);
    RBAR();

    // ---- staging + publish ----
    if (t + 2 < NT) {
      STAGE(t + 2);                                    // overwrites buf[t]
      asm volatile("s_waitcnt vmcnt(8)" ::: "memory"); // drains STAGE(t+1)
    } else {
      asm volatile("s_waitcnt vmcnt(0)" ::: "memory");
    }
    RBAR();                                            // publish buf[t+1]

    // ---- Q(1,0): register-only tail after publish ----
    __builtin_amdgcn_s_setprio(1);
#pragma unroll
    for (int f = 0; f < 4; ++f)
#pragma unroll
      for (int gg = 0; gg < 2; ++gg) {
        f32x4 c = acc[4 + f][gg];
        c = __builtin_amdgcn_mfma_f32_16x16x32_bf16(av1[f][0], b0[gg][0], c, 0, 0, 0);
        c = __builtin_amdgcn_mfma_f32_16x16x32_bf16(av1[f][1], b0[gg][1], c, 0, 0, 0);
        acc[4 + f][gg] = c;
      }
    __builtin_amdgcn_s_setprio(0);
  }
}

// ---------------- unified in_proj GEMM (256x256 tiles) ----------------
// grid 1536, XCD-swizzled: xcd=g&7, u=g>>3, mrow=xcd+8*(u/12), c=u%12.
// c<8 : paired tile, B = [W_B rows c*128.. (128) ; W_x rows 2048+c*128.. (128)];
//       epilogue Bx = (Bg+b)*(xg+b)
// c>=8: plain tile,  B = W_C rows (c-8)*256..; epilogue Cg = acc+b
__global__ __launch_bounds__(512, 2) void gemm_inproj(const unsigned short* __restrict__ A,
                                                      const unsigned short* __restrict__ Wb,
                                                      const float* __restrict__ bin,
                                                      unsigned short* __restrict__ Bx,
                                                      unsigned short* __restrict__ Cg) {
  __shared__ __align__(16) char smem[131072];

  const int g  = blockIdx.x;
  const int u  = g >> 3;
  const int m0 = ((g & 7) + 8 * (u / 12)) * 256;
  const int c  = u % 12;
  const bool paired = (c < 8);

  const int tid  = threadIdx.x;
  const int lane = tid & 63;
  const int srow = ((tid >> 6) << 3) + (lane >> 3);      // staging row (0..63, +i*64)
  const int sch  = (lane & 7) ^ (lane >> 3);             // pre-swizzled source chunk

  const unsigned short* aBase = A + (long)(m0 + srow) * K_ + sch * 8;
  const unsigned short *b0p, *b1p, *b2p, *b3p;
  int n0;
  if (paired) {
    n0  = c * 128;
    b0p = Wb + (long)(n0 + srow) * K_ + sch * 8;           // W_B rows 0..127
    b1p = b0p + (long)64 * K_;
    b2p = Wb + (long)(2048 + n0 + srow) * K_ + sch * 8;    // W_x rows 128..255
    b3p = b2p + (long)64 * K_;
  } else {
    n0  = (c - 8) * 256;
    b0p = Wb + (long)(1024 + n0 + srow) * K_ + sch * 8;    // W_C rows
    b1p = b0p + (long)64 * K_;
    b2p = b0p + (long)128 * K_;
    b3p = b0p + (long)192 * K_;
  }

  f32x4 acc[8][4] = {};
  gemm_core256(smem, aBase, b0p, b1p, b2p, b3p, acc);

  // ---- epilogue: LDS transpose (32 rows x 256 cols fp32), fused bias + gate ----
  const int wm = (tid >> 6) >> 2, wn = (tid >> 6) & 3;
  const int quad = lane >> 4, l16 = lane & 15;
  float* tr = (float*)smem;

  float bvv[4];
#pragma unroll
  for (int ni = 0; ni < 4; ++ni) {
    int col = wn * 64 + ni * 16 + l16;
    bvv[ni] = paired ? ((col < 128) ? bin[n0 + col] : bin[2048 + n0 + col - 128])
                     : bin[1024 + n0 + col];
  }

  const int trr   = tid >> 4;
  const int tcc   = tid & 15;
  const int growb = m0 + ((trr >> 4) << 7) + (trr & 15);

#pragma unroll
  for (int mi = 0; mi < 8; ++mi) {
    __syncthreads();
#pragma unroll
    for (int ni = 0; ni < 4; ++ni) {
      int col = wn * 64 + ni * 16 + l16;
      f32x4 v = acc[mi][ni];
#pragma unroll
      for (int r = 0; r < 4; ++r)
        tr[(wm * 16 + quad * 4 + r) * 260 + col] = v[r] + bvv[ni];
    }
    __syncthreads();

    const int grow = growb + mi * 16;
    if (paired) {
#pragma unroll
      for (int j = 0; j < 2; ++j) {
        int cc = tcc * 4 + j * 64;
        f32x4 bg = *(const f32x4*)&tr[trr * 260 + cc];
        f32x4 xg = *(const f32x4*)&tr[trr * 260 + 128 + cc];
        ushort4 o;
        o.x = f2bf(bg[0] * xg[0]); o.y = f2bf(bg[1] * xg[1]);
        o.z = f2bf(bg[2] * xg[2]); o.w = f2bf(bg[3] * xg[3]);
        *(ushort4*)&Bx[(long)grow * D_ + n0 + cc] = o;
      }
    } else {
#pragma unroll
      for (int j = 0; j < 4; ++j) {
        int cc = tcc * 4 + j * 64;
        f32x4 v = *(const f32x4*)&tr[trr * 260 + cc];
        ushort4 o;
        o.x = f2bf(v[0]); o.y = f2bf(v[1]); o.z = f2bf(v[2]); o.w = f2bf(v[3]);
        *(ushort4*)&Cg[(long)grow * D_ + n0 + cc] = o;
      }
    }
  }
}

// ---------------- streaming causal conv + gate ----------------
__global__ __launch_bounds__(256) void conv_mul(const unsigned short* __restrict__ Bx,
                                                const unsigned short* __restrict__ Cg,
                                                const float* __restrict__ wconv,
                                                unsigned short* __restrict__ y) {
  __shared__ float wt[3][D_];
  for (int i = threadIdx.x; i < D_; i += 256) {
    wt[0][i] = wconv[i * 3 + 0];
    wt[1][i] = wconv[i * 3 + 1];
    wt[2][i] = wconv[i * 3 + 2];
  }
  __syncthreads();

  int idx = blockIdx.x * 256 + threadIdx.x;   // [0, 32768*128)
  int bl  = idx >> 7;
  int d8  = (idx & 127) * 8;
  int l   = bl & (LSEQ - 1);

  typedef unsigned short us8 __attribute__((ext_vector_type(8)));
  us8 zz = {0, 0, 0, 0, 0, 0, 0, 0};
  us8 x0 = *(const us8*)&Bx[(long)bl * D_ + d8];
  us8 x1 = (l >= 1) ? *(const us8*)&Bx[(long)(bl - 1) * D_ + d8] : zz;
  us8 x2 = (l >= 2) ? *(const us8*)&Bx[(long)(bl - 2) * D_ + d8] : zz;
  us8 cg = *(const us8*)&Cg[(long)bl * D_ + d8];

  us8 o;
#pragma unroll
  for (int j = 0; j < 8; ++j) {
    float conv = wt[0][d8 + j] * bf2f(x2[j]) + wt[1][d8 + j] * bf2f(x1[j])
               + wt[2][d8 + j] * bf2f(x0[j]);
    o[j] = f2bf(bf2f(cg[j]) * conv);
  }
  *(us8*)&y[(long)bl * D_ + d8] = o;
}

// ---------------- out_proj GEMM (256x256 tiles, fp32 out) ----------------
// grid 512, XCD-swizzled: mrow=(g&7)+8*((g>>3)>>2), c=(g>>3)&3
__global__ __launch_bounds__(512, 2) void gemm_out(const unsigned short* __restrict__ A,
                                                   const unsigned short* __restrict__ Wb,
                                                   const float* __restrict__ bias,
                                                   float* __restrict__ Out) {
  __shared__ __align__(16) char smem[131072];

  const int g  = blockIdx.x;
  const int u  = g >> 3;
  const int m0 = ((g & 7) + 8 * (u >> 2)) * 256;
  const int n0 = (u & 3) * 256;

  const int tid  = threadIdx.x;
  const int lane = tid & 63;
  const int srow = ((tid >> 6) << 3) + (lane >> 3);
  const int sch  = (lane & 7) ^ (lane >> 3);

  const unsigned short* aBase = A + (long)(m0 + srow) * K_ + sch * 8;
  const unsigned short* b0p   = Wb + (long)(n0 + srow) * K_ + sch * 8;

  f32x4 acc[8][4] = {};
  gemm_core256(smem, aBase, b0p, b0p + (long)64 * K_, b0p + (long)128 * K_,
               b0p + (long)192 * K_, acc);

  const int wm = (tid >> 6) >> 2, wn = (tid >> 6) & 3;
  const int quad = lane >> 4, l16 = lane & 15;
  float* tr = (float*)smem;

  float bvv[4];
#pragma unroll
  for (int ni = 0; ni < 4; ++ni)
    bvv[ni] = bias[n0 + wn * 64 + ni * 16 + l16];

  const int trr   = tid >> 4;
  const int tcc   = tid & 15;
  const int growb = m0 + ((trr >> 4) << 7) + (trr & 15);

#pragma unroll
  for (int mi = 0; mi < 8; ++mi) {
    __syncthreads();
#pragma unroll
    for (int ni = 0; ni < 4; ++ni) {
      int col = wn * 64 + ni * 16 + l16;
      f32x4 v = acc[mi][ni];
#pragma unroll
      for (int r = 0; r < 4; ++r)
        tr[(wm * 16 + quad * 4 + r) * 260 + col] = v[r] + bvv[ni];
    }
    __syncthreads();

    const int grow = growb + mi * 16;
#pragma unroll
    for (int j = 0; j < 4; ++j) {
      int cc = tcc * 4 + j * 64;
      *(f32x4*)&Out[(long)grow * D_ + n0 + cc] = *(const f32x4*)&tr[trr * 260 + cc];
    }
  }
}

// ---------------- launch ----------------
extern "C" void kernel_launch(void* const* d_in, const int* in_sizes, int n_in,
                              void* d_out, int out_size, void* d_ws, size_t ws_size,
                              hipStream_t stream) {
  const float* x     = (const float*)d_in[0];
  const float* Win   = (const float*)d_in[1];
  const float* bin   = (const float*)d_in[2];
  const float* wconv = (const float*)d_in[3];
  const float* Wout  = (const float*)d_in[4];
  const float* bout  = (const float*)d_in[5];

  char* ws = (char*)d_ws;
  // ws: x_b 67,108,864 | Win_b 6,291,456 | Wout_b 2,097,152 | Bx 67,108,864 | Cg 67,108,864 | y 67,108,864
  unsigned short* x_b    = (unsigned short*)(ws);
  unsigned short* Win_b  = (unsigned short*)(ws + 67108864);
  unsigned short* Wout_b = (unsigned short*)(ws + 73400320);
  unsigned short* Bx_b   = (unsigned short*)(ws + 75497472);
  unsigned short* Cg_b   = (unsigned short*)(ws + 142606336);
  unsigned short* y_b    = (unsigned short*)(ws + 209715200);

  cvt_all<<<(NX4 + NW4 + NO4) / 256, 256, 0, stream>>>(x, Win, Wout, x_b, Win_b, Wout_b);

  gemm_inproj<<<1536, 512, 0, stream>>>(x_b, Win_b, bin, Bx_b, Cg_b);

  conv_mul<<<(M_ * (D_ / 8)) / 256, 256, 0, stream>>>(Bx_b, Cg_b, wconv, y_b);

  gemm_out<<<512, 512, 0, stream>>>(y_b, Wout_b, bout, (float*)d_out);
}